// Round 3
// baseline (162.245 us; speedup 1.0000x reference)
//
#include <hip/hip_runtime.h>
#include <hip/hip_bf16.h>

#define N_ROWS 8192
#define DIM 1024
#define TEMP_INV (1.0f / 0.07f)
#define NT 32                 // 8192 / 256 tiles per dim
#define NBLK (NT * (NT + 1) / 2)   // 528
#define KT 16                 // DIM / 64 K-tiles

typedef __attribute__((ext_vector_type(8))) __bf16 bf16x8;
typedef __attribute__((ext_vector_type(4))) float f32x4;

__device__ inline void gload_lds16(const __hip_bfloat16* g, __hip_bfloat16* l) {
    __builtin_amdgcn_global_load_lds(
        (const __attribute__((address_space(1))) void*)g,
        (__attribute__((address_space(3))) void*)l,
        16, 0, 0);
}

// ---------------- Kernel 1: L2-normalize rows, write bf16 ----------------
__global__ __launch_bounds__(256) void knorm(const float* __restrict__ X,
                                             __hip_bfloat16* __restrict__ Y) {
    const int row = blockIdx.x;
    const int t = threadIdx.x;
    const float* x = X + (size_t)row * DIM;
    float4 v = reinterpret_cast<const float4*>(x)[t];
    float ss = v.x * v.x + v.y * v.y + v.z * v.z + v.w * v.w;
    #pragma unroll
    for (int off = 32; off > 0; off >>= 1) ss += __shfl_down(ss, off);
    __shared__ float red[4];
    if ((t & 63) == 0) red[t >> 6] = ss;
    __syncthreads();
    float tot = red[0] + red[1] + red[2] + red[3];
    float inv = 1.0f / fmaxf(sqrtf(tot), 1e-12f);
    __hip_bfloat16 o[4];
    o[0] = __float2bfloat16(v.x * inv);
    o[1] = __float2bfloat16(v.y * inv);
    o[2] = __float2bfloat16(v.z * inv);
    o[3] = __float2bfloat16(v.w * inv);
    reinterpret_cast<ushort4*>(Y + (size_t)row * DIM)[t] =
        *reinterpret_cast<ushort4*>(o);
}

// ---------------- Kernel 2: 256x256 8-phase fused GEMM + reductions ------
// BM=BN=256, BK=64, 8 waves (2Mx4N), per-wave 128x64 output as 8x4 16x16
// fragments. LDS: 2 dbuf x (A 32KB + B 32KB) = 128 KiB, XOR-swizzled
// (byte ^= (row&7)<<4) via pre-swizzled global source (linear LDS dest).
// Per-wave M rows interleaved across tile halves: mh0 = wr*64..+63 (half0),
// mh1 = 128+wr*64..+63 (half1); N: nh0 = wc*32..+31 (B half0), nh1 = 128+
// wc*32..+31 (B half1). So each LDS half-tile region dies after exactly one
// phase, enabling 1-half-tile-per-phase staging with vmcnt(6) per K-tile.
struct SMem {
    __hip_bfloat16 tiles[2][2][16384];  // [buf][A/B][32KB]
    int labR[256];
    int labC[256];
};

__global__ __launch_bounds__(512, 2) void kgemm(const __hip_bfloat16* __restrict__ F,
                                                const int* __restrict__ labels,
                                                float* __restrict__ S1,
                                                float* __restrict__ S2,
                                                float* __restrict__ CNT) {
    __shared__ SMem sm;

    // XCD-aware swizzle (528 = 8*66, bijective)
    const int bid0 = blockIdx.x;
    const int bid = (bid0 & 7) * (NBLK / 8) + (bid0 >> 3);
    // triangular map: bid -> (bx>=by)
    int a = (int)((sqrtf(8.0f * (float)bid + 1.0f) - 1.0f) * 0.5f);
    while ((a + 1) * (a + 2) / 2 <= bid) ++a;
    while (a * (a + 1) / 2 > bid) --a;
    const int bx = a;
    const int by = bid - a * (a + 1) / 2;
    const bool diag = (bx == by);
    const int rowBase = by * 256;
    const int colBase = bx * 256;

    const int t = threadIdx.x;
    const int lane = t & 63;
    const int wid = t >> 6;        // 0..7
    const int wr = wid >> 2;       // 0..1  (M wave row)
    const int wc = wid & 3;        // 0..3  (N wave col)
    const int l16 = lane & 15;
    const int g16 = lane >> 4;     // 0..3

    if (t < 256) sm.labR[t] = labels[rowBase + t];
    else         sm.labC[t - 256] = labels[colBase + (t - 256)];

    // per-thread ds_read addressing (bytes)
    const int xorm = (l16 & 7) << 4;
    const int colS0 = (g16 * 16) ^ xorm;          // k-slice 0
    const int colS1 = (64 + g16 * 16) ^ xorm;     // k-slice 1
    int rowA[8], rowB[4];
    #pragma unroll
    for (int m = 0; m < 8; ++m) {
        const int rb = (m < 4) ? (wr * 64 + m * 16) : (128 + wr * 64 + (m - 4) * 16);
        rowA[m] = (rb + l16) * 128;
    }
    #pragma unroll
    for (int n = 0; n < 4; ++n) {
        const int rb = (n < 2) ? (wc * 32 + n * 16) : (128 + wc * 32 + (n - 2) * 16);
        rowB[n] = (rb + l16) * 128;
    }

    // per-thread staging addressing: thread covers lin = t*16 and t*16+8192
    const int lin0 = t * 16;
    const int sr0 = lin0 >> 7;                    // 0..63
    const int scel = ((lin0 & 127) ^ ((sr0 & 7) << 4)) >> 1;  // source elem in row

    // stage one half-tile (2 x global_load_lds_dwordx4 per thread)
    auto stage = [&](int mat, int bufsel, int half, int kt, int baseRow) {
        if (kt < KT) {
            char* ldsb = (char*)&sm.tiles[bufsel][mat][0] + half * 16384;
            const __hip_bfloat16* src = F + (size_t)(baseRow + half * 128 + sr0) * DIM
                                          + kt * 64 + scel;
            gload_lds16(src, (__hip_bfloat16*)(ldsb + lin0));
            gload_lds16(src + (size_t)64 * DIM, (__hip_bfloat16*)(ldsb + lin0 + 8192));
        }
    };

    f32x4 acc[8][4];
    #pragma unroll
    for (int m = 0; m < 8; ++m)
        #pragma unroll
        for (int n = 0; n < 4; ++n)
            acc[m][n] = f32x4{0.f, 0.f, 0.f, 0.f};

    // prologue: tile0 all 4 halves, tile1 A0,B0,B1 (A1 staged at u=0 ph1)
    stage(0, 0, 0, 0, rowBase); stage(0, 0, 1, 0, rowBase);
    stage(1, 0, 0, 0, colBase); stage(1, 0, 1, 0, colBase);
    stage(0, 1, 0, 1, rowBase); stage(1, 1, 0, 1, colBase); stage(1, 1, 1, 1, colBase);
    asm volatile("s_waitcnt vmcnt(6)" ::: "memory");
    __syncthreads();

    bf16x8 av[4][2], b0[2][2], b1[2][2];

    #pragma unroll 2
    for (int u = 0; u < KT; ++u) {
        const int b = u & 1;
        char* tA = (char*)&sm.tiles[b][0][0];
        char* tB = (char*)&sm.tiles[b][1][0];

        // ---- phase 1: read A-mh0 + B-nh0, stage A1(u+1); mfma mh0 x nh0 ----
        #pragma unroll
        for (int m = 0; m < 4; ++m) {
            av[m][0] = *(const bf16x8*)(tA + rowA[m] + colS0);
            av[m][1] = *(const bf16x8*)(tA + rowA[m] + colS1);
        }
        #pragma unroll
        for (int n = 0; n < 2; ++n) {
            b0[n][0] = *(const bf16x8*)(tB + rowB[n] + colS0);
            b0[n][1] = *(const bf16x8*)(tB + rowB[n] + colS1);
        }
        stage(0, (u + 1) & 1, 1, u + 1, rowBase);
        __builtin_amdgcn_s_barrier();
        asm volatile("s_waitcnt lgkmcnt(0)" ::: "memory");
        __builtin_amdgcn_s_setprio(1);
        #pragma unroll
        for (int m = 0; m < 4; ++m)
            #pragma unroll
            for (int n = 0; n < 2; ++n) {
                acc[m][n] = __builtin_amdgcn_mfma_f32_16x16x32_bf16(av[m][0], b0[n][0], acc[m][n], 0, 0, 0);
                acc[m][n] = __builtin_amdgcn_mfma_f32_16x16x32_bf16(av[m][1], b0[n][1], acc[m][n], 0, 0, 0);
            }
        __builtin_amdgcn_s_setprio(0);
        __builtin_amdgcn_s_barrier();

        // ---- phase 2: read B-nh1, stage A0(u+2); mfma mh0 x nh1 ----
        #pragma unroll
        for (int n = 0; n < 2; ++n) {
            b1[n][0] = *(const bf16x8*)(tB + rowB[n + 2] + colS0);
            b1[n][1] = *(const bf16x8*)(tB + rowB[n + 2] + colS1);
        }
        stage(0, b, 0, u + 2, rowBase);
        __builtin_amdgcn_s_barrier();
        asm volatile("s_waitcnt lgkmcnt(0)" ::: "memory");
        __builtin_amdgcn_s_setprio(1);
        #pragma unroll
        for (int m = 0; m < 4; ++m)
            #pragma unroll
            for (int n = 0; n < 2; ++n) {
                acc[m][n + 2] = __builtin_amdgcn_mfma_f32_16x16x32_bf16(av[m][0], b1[n][0], acc[m][n + 2], 0, 0, 0);
                acc[m][n + 2] = __builtin_amdgcn_mfma_f32_16x16x32_bf16(av[m][1], b1[n][1], acc[m][n + 2], 0, 0, 0);
            }
        __builtin_amdgcn_s_setprio(0);
        __builtin_amdgcn_s_barrier();

        // ---- phase 3: read A-mh1, stage B0(u+2); mfma mh1 x nh1 ----
        #pragma unroll
        for (int m = 0; m < 4; ++m) {
            av[m][0] = *(const bf16x8*)(tA + rowA[m + 4] + colS0);
            av[m][1] = *(const bf16x8*)(tA + rowA[m + 4] + colS1);
        }
        stage(1, b, 0, u + 2, colBase);
        __builtin_amdgcn_s_barrier();
        asm volatile("s_waitcnt lgkmcnt(0)" ::: "memory");
        __builtin_amdgcn_s_setprio(1);
        #pragma unroll
        for (int m = 0; m < 4; ++m)
            #pragma unroll
            for (int n = 0; n < 2; ++n) {
                acc[m + 4][n + 2] = __builtin_amdgcn_mfma_f32_16x16x32_bf16(av[m][0], b1[n][0], acc[m + 4][n + 2], 0, 0, 0);
                acc[m + 4][n + 2] = __builtin_amdgcn_mfma_f32_16x16x32_bf16(av[m][1], b1[n][1], acc[m + 4][n + 2], 0, 0, 0);
            }
        __builtin_amdgcn_s_setprio(0);
        __builtin_amdgcn_s_barrier();

        // ---- phase 4: stage B1(u+2); mfma mh1 x nh0; vmcnt(6) ----
        stage(1, b, 1, u + 2, colBase);
        __builtin_amdgcn_s_barrier();
        asm volatile("s_waitcnt lgkmcnt(0)" ::: "memory");
        __builtin_amdgcn_s_setprio(1);
        #pragma unroll
        for (int m = 0; m < 4; ++m)
            #pragma unroll
            for (int n = 0; n < 2; ++n) {
                acc[m + 4][n] = __builtin_amdgcn_mfma_f32_16x16x32_bf16(av[m][0], b0[n][0], acc[m + 4][n], 0, 0, 0);
                acc[m + 4][n] = __builtin_amdgcn_mfma_f32_16x16x32_bf16(av[m][1], b0[n][1], acc[m + 4][n], 0, 0, 0);
            }
        __builtin_amdgcn_s_setprio(0);
        asm volatile("s_waitcnt vmcnt(6)" ::: "memory");
        __builtin_amdgcn_s_barrier();
    }

    // ---------------- epilogue: streaming row/col reductions ----------------
    // row(m,reg) = rowBase + rbaseA(m) + g16*4 + reg ; col(n) = colBase + rbaseB(n) + l16
    int labCn[4], cbase[4];
    #pragma unroll
    for (int n = 0; n < 4; ++n) {
        const int rb = (n < 2) ? (wc * 32 + n * 16) : (128 + wc * 32 + (n - 2) * 16);
        cbase[n] = rb + l16;
        labCn[n] = sm.labC[cbase[n]];
    }

    float colE[4] = {0.f, 0.f, 0.f, 0.f};
    float colS2[4] = {0.f, 0.f, 0.f, 0.f};
    float colC[4] = {0.f, 0.f, 0.f, 0.f};

    #pragma unroll
    for (int m = 0; m < 8; ++m) {
        const int rbA = ((m < 4) ? (wr * 64 + m * 16) : (128 + wr * 64 + (m - 4) * 16)) + g16 * 4;
        #pragma unroll
        for (int reg = 0; reg < 4; ++reg) {
            const int row = rowBase + rbA + reg;
            const int labRow = sm.labR[rbA + reg];
            float e = 0.f, s2 = 0.f, c = 0.f;
            #pragma unroll
            for (int n = 0; n < 4; ++n) {
                const float sim = acc[m][n][reg] * TEMP_INV;
                const int col = colBase + cbase[n];
                const float ex = __expf(sim);
                const bool same = (labRow == labCn[n]);
                if (diag) {
                    if (row != col) e += ex;
                } else {
                    e += ex;
                    colE[n] += ex;
                }
                if (same) {
                    s2 += sim; c += 1.0f;
                    if (!diag) { colS2[n] += sim; colC[n] += 1.0f; }
                }
            }
            #pragma unroll
            for (int off = 1; off < 16; off <<= 1) {
                e  += __shfl_xor(e, off);
                s2 += __shfl_xor(s2, off);
                c  += __shfl_xor(c, off);
            }
            if (l16 == 0) {
                atomicAdd(&S1[row], e);
                atomicAdd(&S2[row], s2);
                atomicAdd(&CNT[row], c);
            }
        }
    }

    if (!diag) {
        #pragma unroll
        for (int n = 0; n < 4; ++n) {
            float ce = colE[n], cs = colS2[n], cc = colC[n];
            #pragma unroll
            for (int off = 16; off < 64; off <<= 1) {
                ce += __shfl_xor(ce, off);
                cs += __shfl_xor(cs, off);
                cc += __shfl_xor(cc, off);
            }
            if (g16 == 0) {
                const int col = colBase + cbase[n];
                atomicAdd(&S1[col], ce);
                atomicAdd(&S2[col], cs);
                atomicAdd(&CNT[col], cc);
            }
        }
    }
}

// ---------------- Kernel 3: finalize ----------------
__global__ __launch_bounds__(256) void kfinal(const float* __restrict__ S1,
                                              const float* __restrict__ S2,
                                              const float* __restrict__ CNT,
                                              float* __restrict__ out) {
    const int t = threadIdx.x;
    float a = 0.f;
    for (int i = t; i < N_ROWS; i += 256) {
        const float cnt = CNT[i];
        const float ld = logf(S1[i] + 1e-12f);
        a += (cnt * ld - S2[i]) / (cnt + 1e-12f);
    }
    #pragma unroll
    for (int off = 32; off > 0; off >>= 1) a += __shfl_down(a, off);
    __shared__ float red[4];
    if ((t & 63) == 0) red[t >> 6] = a;
    __syncthreads();
    if (t == 0) out[0] = (red[0] + red[1] + red[2] + red[3]) / (float)N_ROWS;
}

extern "C" void kernel_launch(void* const* d_in, const int* in_sizes, int n_in,
                              void* d_out, int out_size, void* d_ws, size_t ws_size,
                              hipStream_t stream) {
    const float* feat = (const float*)d_in[0];
    const int* labels = (const int*)d_in[1];
    float* out = (float*)d_out;

    __hip_bfloat16* Fn = (__hip_bfloat16*)d_ws;
    float* S1 = (float*)((char*)d_ws + (size_t)N_ROWS * DIM * 2);
    float* S2 = S1 + N_ROWS;
    float* CNT = S2 + N_ROWS;

    hipMemsetAsync(S1, 0, 3 * N_ROWS * sizeof(float), stream);
    knorm<<<N_ROWS, 256, 0, stream>>>(feat, Fn);
    kgemm<<<NBLK, 512, 0, stream>>>(Fn, labels, S1, S2, CNT);
    kfinal<<<1, 256, 0, stream>>>(S1, S2, CNT, out);
}

// Round 4
// 117.316 us; speedup vs baseline: 1.3830x; 1.3830x over previous
//
#include <hip/hip_runtime.h>
#include <hip/hip_bf16.h>

#define N_ROWS 8192
#define DIM 1024
#define TEMP_INV (1.0f / 0.07f)

typedef __attribute__((ext_vector_type(4))) int i32x4;

__device__ inline void gload_lds16(const void* g, void* l) {
    __builtin_amdgcn_global_load_lds(
        (const __attribute__((address_space(1))) void*)g,
        (__attribute__((address_space(3))) void*)l,
        16, 0, 0);
}

// ------- Kernel 1: L2-normalize rows, quantize to int8 + per-row scale ----
// q = round(f / s), s = max|x| / (127 * ||x||)  =>  q*s == x/||x|| exactly up
// to rounding. sim(i,j) = (qi . qj) * s_i * s_j.
__global__ __launch_bounds__(256) void knorm(const float* __restrict__ X,
                                             char* __restrict__ Q,
                                             float* __restrict__ SC) {
    const int row = blockIdx.x;
    const int t = threadIdx.x;
    const float* x = X + (size_t)row * DIM;
    float4 v = reinterpret_cast<const float4*>(x)[t];
    float ss = v.x * v.x + v.y * v.y + v.z * v.z + v.w * v.w;
    float mx = fmaxf(fmaxf(fabsf(v.x), fabsf(v.y)), fmaxf(fabsf(v.z), fabsf(v.w)));
    #pragma unroll
    for (int off = 32; off > 0; off >>= 1) {
        ss += __shfl_down(ss, off);
        mx = fmaxf(mx, __shfl_down(mx, off));
    }
    __shared__ float redS[4], redM[4];
    if ((t & 63) == 0) { redS[t >> 6] = ss; redM[t >> 6] = mx; }
    __syncthreads();
    float tot = redS[0] + redS[1] + redS[2] + redS[3];
    float amax = fmaxf(fmaxf(redM[0], redM[1]), fmaxf(redM[2], redM[3]));
    amax = fmaxf(amax, 1e-20f);
    const float norm = fmaxf(sqrtf(tot), 1e-12f);
    const float qmul = 127.0f / amax;                 // x -> q
    const float scale = amax / (127.0f * norm);       // q -> f
    int q0 = (int)rintf(v.x * qmul);
    int q1 = (int)rintf(v.y * qmul);
    int q2 = (int)rintf(v.z * qmul);
    int q3 = (int)rintf(v.w * qmul);
    q0 = min(max(q0, -127), 127); q1 = min(max(q1, -127), 127);
    q2 = min(max(q2, -127), 127); q3 = min(max(q3, -127), 127);
    const unsigned packed = (unsigned)(q0 & 0xff) | ((unsigned)(q1 & 0xff) << 8) |
                            ((unsigned)(q2 & 0xff) << 16) | ((unsigned)(q3 & 0xff) << 24);
    reinterpret_cast<unsigned*>(Q + (size_t)row * DIM)[t] = packed;
    if (t == 0) SC[row] = scale;
}

// ------- Kernel 2: fused int8 GEMM (q q^T) + streaming reductions ---------
// Proven r2 shell: triangular grid, 128x128 tile, BK=64 (i8), 4 waves (2x2),
// per-wave 64x64 via 4x4 fragments of mfma_i32_16x16x64_i8 (K=64/instr).
// Stage/LDS addressing byte-identical to the validated bf16 BK=32 kernel.
__global__ __launch_bounds__(256) void kgemm(const char* __restrict__ Q,
                                             const float* __restrict__ SC,
                                             const int* __restrict__ labels,
                                             float* __restrict__ S1,
                                             float* __restrict__ S2,
                                             float* __restrict__ CNT) {
    constexpr int BM = 128, BK = 64;
    __shared__ __align__(16) char As[BM * BK];
    __shared__ __align__(16) char Bs[BM * BK];
    __shared__ int labR[BM];
    __shared__ int labC[BM];
    __shared__ float scR[BM];
    __shared__ float scCs[BM];

    // triangular map: bid -> (bx >= by)
    const int bid = blockIdx.x;
    int a = (int)((sqrtf(8.0f * (float)bid + 1.0f) - 1.0f) * 0.5f);
    while ((a + 1) * (a + 2) / 2 <= bid) ++a;
    while (a * (a + 1) / 2 > bid) --a;
    const int bx = a;
    const int by = bid - a * (a + 1) / 2;
    const bool diag = (bx == by);
    const int rowBase = by * BM;
    const int colBase = bx * BM;

    const int t = threadIdx.x;
    const int lane = t & 63;
    const int wid = t >> 6;
    const int wr = wid >> 1;
    const int wc = wid & 1;
    const int l16 = lane & 15;
    const int g16 = lane >> 4;

    if (t < 128) { labR[t] = labels[rowBase + t]; scR[t] = SC[rowBase + t]; }
    else { labC[t - 128] = labels[colBase + (t - 128)]; scCs[t - 128] = SC[colBase + (t - 128)]; }

    i32x4 acc[4][4];
    #pragma unroll
    for (int m = 0; m < 4; ++m)
        #pragma unroll
        for (int n = 0; n < 4; ++n)
            acc[m][n] = i32x4{0, 0, 0, 0};

    // staging: thread covers 2 x 16B per matrix per K-step
    const int srow = t >> 2;            // 0..63
    const int scol = (t & 3) * 16;      // 0/16/32/48 (bytes within 64B row)

    for (int kt = 0; kt < DIM / BK; ++kt) {
        const int k0 = kt * BK;
        #pragma unroll
        for (int i = 0; i < 2; ++i) {
            const int r = i * 64 + srow;
            gload_lds16(Q + (size_t)(rowBase + r) * DIM + k0 + scol, &As[r * BK + scol]);
            gload_lds16(Q + (size_t)(colBase + r) * DIM + k0 + scol, &Bs[r * BK + scol]);
        }
        __syncthreads();

        i32x4 av[4], bv[4];
        #pragma unroll
        for (int m = 0; m < 4; ++m)
            av[m] = *reinterpret_cast<const i32x4*>(&As[(wr * 64 + m * 16 + l16) * BK + g16 * 16]);
        #pragma unroll
        for (int n = 0; n < 4; ++n)
            bv[n] = *reinterpret_cast<const i32x4*>(&Bs[(wc * 64 + n * 16 + l16) * BK + g16 * 16]);
        #pragma unroll
        for (int m = 0; m < 4; ++m)
            #pragma unroll
            for (int n = 0; n < 4; ++n)
                acc[m][n] = __builtin_amdgcn_mfma_i32_16x16x64_i8(av[m], bv[n], acc[m][n], 0, 0, 0);
        __syncthreads();
    }

    // Epilogue. C/D layout (dtype-independent):
    //   col = colBase + wc*64 + n*16 + l16 ; row = rowBase + wr*64 + m*16 + g16*4 + reg
    int labCn[4];
    float scCn[4];
    #pragma unroll
    for (int n = 0; n < 4; ++n) {
        const int c = wc * 64 + n * 16 + l16;
        labCn[n] = labC[c];
        scCn[n] = scCs[c] * TEMP_INV;
    }

    float colE[4]  = {0.f, 0.f, 0.f, 0.f};
    float colS2[4] = {0.f, 0.f, 0.f, 0.f};
    float colC[4]  = {0.f, 0.f, 0.f, 0.f};

    #pragma unroll
    for (int m = 0; m < 4; ++m) {
        const int rloc = wr * 64 + m * 16 + g16 * 4;
        #pragma unroll
        for (int reg = 0; reg < 4; ++reg) {
            const int row = rowBase + rloc + reg;
            const int labRow = labR[rloc + reg];
            const float sRow = scR[rloc + reg];
            float e = 0.f, s2 = 0.f, c = 0.f;
            #pragma unroll
            for (int n = 0; n < 4; ++n) {
                const float sim = (float)acc[m][n][reg] * sRow * scCn[n];
                const int col = colBase + wc * 64 + n * 16 + l16;
                const float ex = __expf(sim);
                const bool same = (labRow == labCn[n]);
                if (diag) {
                    if (row != col) e += ex;
                } else {
                    e += ex;
                    colE[n] += ex;
                }
                if (same) {
                    s2 += sim; c += 1.0f;
                    if (!diag) { colS2[n] += sim; colC[n] += 1.0f; }
                }
            }
            #pragma unroll
            for (int off = 1; off < 16; off <<= 1) {
                e  += __shfl_xor(e, off);
                s2 += __shfl_xor(s2, off);
                c  += __shfl_xor(c, off);
            }
            if (l16 == 0) {
                atomicAdd(&S1[row], e);
                atomicAdd(&S2[row], s2);
                atomicAdd(&CNT[row], c);
            }
        }
    }

    if (!diag) {
        #pragma unroll
        for (int n = 0; n < 4; ++n) {
            float ce = colE[n], cs = colS2[n], cc = colC[n];
            #pragma unroll
            for (int off = 16; off < 64; off <<= 1) {
                ce += __shfl_xor(ce, off);
                cs += __shfl_xor(cs, off);
                cc += __shfl_xor(cc, off);
            }
            if (g16 == 0) {
                const int col = colBase + wc * 64 + n * 16 + l16;
                atomicAdd(&S1[col], ce);
                atomicAdd(&S2[col], cs);
                atomicAdd(&CNT[col], cc);
            }
        }
    }
}

// ---------------- Kernel 3: finalize ----------------
__global__ __launch_bounds__(256) void kfinal(const float* __restrict__ S1,
                                              const float* __restrict__ S2,
                                              const float* __restrict__ CNT,
                                              float* __restrict__ out) {
    const int t = threadIdx.x;
    float a = 0.f;
    for (int i = t; i < N_ROWS; i += 256) {
        const float cnt = CNT[i];
        const float ld = logf(S1[i] + 1e-12f);
        a += (cnt * ld - S2[i]) / (cnt + 1e-12f);
    }
    #pragma unroll
    for (int off = 32; off > 0; off >>= 1) a += __shfl_down(a, off);
    __shared__ float red[4];
    if ((t & 63) == 0) red[t >> 6] = a;
    __syncthreads();
    if (t == 0) out[0] = (red[0] + red[1] + red[2] + red[3]) / (float)N_ROWS;
}

extern "C" void kernel_launch(void* const* d_in, const int* in_sizes, int n_in,
                              void* d_out, int out_size, void* d_ws, size_t ws_size,
                              hipStream_t stream) {
    const float* feat = (const float*)d_in[0];
    const int* labels = (const int*)d_in[1];
    float* out = (float*)d_out;

    char* Q = (char*)d_ws;
    float* SC = (float*)((char*)d_ws + (size_t)N_ROWS * DIM);
    float* S1 = SC + N_ROWS;
    float* S2 = S1 + N_ROWS;
    float* CNT = S2 + N_ROWS;

    constexpr int NT = N_ROWS / 128;              // 64 tiles per dim
    constexpr int NBLK = NT * (NT + 1) / 2;       // 2080 triangular blocks

    hipMemsetAsync(S1, 0, 3 * N_ROWS * sizeof(float), stream);
    knorm<<<N_ROWS, 256, 0, stream>>>(feat, Q, SC);
    kgemm<<<NBLK, 256, 0, stream>>>(Q, SC, labels, S1, S2, CNT);
    kfinal<<<1, 256, 0, stream>>>(S1, S2, CNT, out);
}

// Round 5
// 77.978 us; speedup vs baseline: 2.0806x; 1.5045x over previous
//
#include <hip/hip_runtime.h>
#include <hip/hip_bf16.h>

#define N_ROWS 8192
#define DIM 1024
#define TEMP_INV (1.0f / 0.07f)

typedef __attribute__((ext_vector_type(4))) int i32x4;

__device__ inline void gload_lds16(const void* g, void* l) {
    __builtin_amdgcn_global_load_lds(
        (const __attribute__((address_space(1))) void*)g,
        (__attribute__((address_space(3))) void*)l,
        16, 0, 0);
}

// ------- Kernel 1: L2-normalize rows, quantize to int8 + per-row scale ----
// Also zeroes S1/S2/CNT (replaces the separate memset dispatch).
__global__ __launch_bounds__(256) void knorm(const float* __restrict__ X,
                                             char* __restrict__ Q,
                                             float* __restrict__ SC,
                                             float* __restrict__ S1,
                                             float* __restrict__ S2,
                                             float* __restrict__ CNT) {
    const int row = blockIdx.x;
    const int t = threadIdx.x;
    const float* x = X + (size_t)row * DIM;
    float4 v = reinterpret_cast<const float4*>(x)[t];
    float ss = v.x * v.x + v.y * v.y + v.z * v.z + v.w * v.w;
    float mx = fmaxf(fmaxf(fabsf(v.x), fabsf(v.y)), fmaxf(fabsf(v.z), fabsf(v.w)));
    #pragma unroll
    for (int off = 32; off > 0; off >>= 1) {
        ss += __shfl_down(ss, off);
        mx = fmaxf(mx, __shfl_down(mx, off));
    }
    __shared__ float redS[4], redM[4];
    if ((t & 63) == 0) { redS[t >> 6] = ss; redM[t >> 6] = mx; }
    __syncthreads();
    float tot = redS[0] + redS[1] + redS[2] + redS[3];
    float amax = fmaxf(fmaxf(redM[0], redM[1]), fmaxf(redM[2], redM[3]));
    amax = fmaxf(amax, 1e-20f);
    const float norm = fmaxf(sqrtf(tot), 1e-12f);
    const float qmul = 127.0f / amax;                 // x -> q
    const float scale = amax / (127.0f * norm);       // q -> f
    int q0 = (int)rintf(v.x * qmul);
    int q1 = (int)rintf(v.y * qmul);
    int q2 = (int)rintf(v.z * qmul);
    int q3 = (int)rintf(v.w * qmul);
    q0 = min(max(q0, -127), 127); q1 = min(max(q1, -127), 127);
    q2 = min(max(q2, -127), 127); q3 = min(max(q3, -127), 127);
    const unsigned packed = (unsigned)(q0 & 0xff) | ((unsigned)(q1 & 0xff) << 8) |
                            ((unsigned)(q2 & 0xff) << 16) | ((unsigned)(q3 & 0xff) << 24);
    reinterpret_cast<unsigned*>(Q + (size_t)row * DIM)[t] = packed;
    if (t == 0) SC[row] = scale;
    if (t == 1) { S1[row] = 0.f; S2[row] = 0.f; CNT[row] = 0.f; }
}

// ------- Kernel 2: fused int8 GEMM (q q^T) + streaming reductions ---------
// 128x128 tile, BK=128 (8 K-iters), 4 waves (2x2), per-wave 64x64 via 4x4
// fragments of mfma_i32_16x16x64_i8 (2 MFMA per fragment pair).
// LDS tiles XOR-swizzled (byte ^= (row&7)<<4) via pre-swizzled global source
// (linear gload_lds dest) + swizzled ds_read address -> 2-way (free) banks.
__global__ __launch_bounds__(256) void kgemm(const char* __restrict__ Q,
                                             const float* __restrict__ SC,
                                             const int* __restrict__ labels,
                                             float* __restrict__ S1,
                                             float* __restrict__ S2,
                                             float* __restrict__ CNT) {
    constexpr int BM = 128, BK = 128;
    __shared__ __align__(16) char As[BM * BK];
    __shared__ __align__(16) char Bs[BM * BK];
    __shared__ int labR[BM];
    __shared__ int labC[BM];
    __shared__ float scR[BM];
    __shared__ float scCs[BM];

    // XCD chunk swizzle (2080 = 8 * 260, bijective), then triangular decode
    const int bid0 = blockIdx.x;
    const int bid = (bid0 & 7) * 260 + (bid0 >> 3);
    int a = (int)((sqrtf(8.0f * (float)bid + 1.0f) - 1.0f) * 0.5f);
    while ((a + 1) * (a + 2) / 2 <= bid) ++a;
    while (a * (a + 1) / 2 > bid) --a;
    const int bx = a;
    const int by = bid - a * (a + 1) / 2;
    const bool diag = (bx == by);
    const int rowBase = by * BM;
    const int colBase = bx * BM;

    const int t = threadIdx.x;
    const int lane = t & 63;
    const int wid = t >> 6;
    const int wr = wid >> 1;
    const int wc = wid & 1;
    const int l16 = lane & 15;
    const int g16 = lane >> 4;

    if (t < 128) { labR[t] = labels[rowBase + t]; scR[t] = SC[rowBase + t]; }
    else { labC[t - 128] = labels[colBase + (t - 128)]; scCs[t - 128] = SC[colBase + (t - 128)]; }

    i32x4 acc[4][4];
    #pragma unroll
    for (int m = 0; m < 4; ++m)
        #pragma unroll
        for (int n = 0; n < 4; ++n)
            acc[m][n] = i32x4{0, 0, 0, 0};

    const int srow = t >> 3;            // 0..31
    const int scolL = (t & 7) * 16;     // linear LDS byte col in [0,128)
    const int xorb = (l16 & 7) << 4;    // read-side swizzle

    for (int kt = 0; kt < DIM / BK; ++kt) {
        const int k0 = kt * BK;
        #pragma unroll
        for (int i = 0; i < 4; ++i) {
            const int r = i * 32 + srow;
            const int sg = scolL ^ ((r & 7) << 4);  // inverse-swizzled source col
            gload_lds16(Q + (size_t)(rowBase + r) * DIM + k0 + sg, &As[r * BK + scolL]);
            gload_lds16(Q + (size_t)(colBase + r) * DIM + k0 + sg, &Bs[r * BK + scolL]);
        }
        __syncthreads();

        #pragma unroll
        for (int kk = 0; kk < 2; ++kk) {
            const int ck = (kk * 64 + g16 * 16) ^ xorb;
            i32x4 av[4], bv[4];
            #pragma unroll
            for (int m = 0; m < 4; ++m)
                av[m] = *reinterpret_cast<const i32x4*>(&As[(wr * 64 + m * 16 + l16) * BK + ck]);
            #pragma unroll
            for (int n = 0; n < 4; ++n)
                bv[n] = *reinterpret_cast<const i32x4*>(&Bs[(wc * 64 + n * 16 + l16) * BK + ck]);
            #pragma unroll
            for (int m = 0; m < 4; ++m)
                #pragma unroll
                for (int n = 0; n < 4; ++n)
                    acc[m][n] = __builtin_amdgcn_mfma_i32_16x16x64_i8(av[m], bv[n], acc[m][n], 0, 0, 0);
        }
        __syncthreads();
    }

    // Epilogue. C/D layout (dtype-independent):
    //   col = colBase + wc*64 + n*16 + l16 ; row = rowBase + wr*64 + m*16 + g16*4 + reg
    int labCn[4];
    float scCn[4];
    #pragma unroll
    for (int n = 0; n < 4; ++n) {
        const int c = wc * 64 + n * 16 + l16;
        labCn[n] = labC[c];
        scCn[n] = scCs[c] * TEMP_INV;
    }

    const unsigned long long grpmask = 0xFFFFull << (g16 * 16);

    float colE[4]  = {0.f, 0.f, 0.f, 0.f};
    float colS2[4] = {0.f, 0.f, 0.f, 0.f};
    float colC[4]  = {0.f, 0.f, 0.f, 0.f};

    #pragma unroll
    for (int m = 0; m < 4; ++m) {
        const int rloc = wr * 64 + m * 16 + g16 * 4;
        #pragma unroll
        for (int reg = 0; reg < 4; ++reg) {
            const int row = rowBase + rloc + reg;
            const int labRow = labR[rloc + reg];
            const float sRow = scR[rloc + reg];
            float e = 0.f, s2 = 0.f, c = 0.f;
            #pragma unroll
            for (int n = 0; n < 4; ++n) {
                const float sim = (float)acc[m][n][reg] * sRow * scCn[n];
                const int col = colBase + wc * 64 + n * 16 + l16;
                const float ex = __expf(sim);
                const bool same = (labRow == labCn[n]);
                if (diag) {
                    if (row != col) e += ex;
                } else {
                    e += ex;
                    colE[n] += ex;
                }
                if (same) {
                    s2 += sim; c += 1.0f;
                    if (!diag) { colS2[n] += sim; colC[n] += 1.0f; }
                }
            }
            // e always reduced; s2/cnt only if any lane in this 16-group matched
            const unsigned long long bal = __ballot(c != 0.f);
            const bool doS = (bal & grpmask) != 0ull;
            #pragma unroll
            for (int off = 1; off < 16; off <<= 1) e += __shfl_xor(e, off);
            if (doS) {
                #pragma unroll
                for (int off = 1; off < 16; off <<= 1) {
                    s2 += __shfl_xor(s2, off);
                    c  += __shfl_xor(c, off);
                }
            }
            if (l16 == 0) {
                atomicAdd(&S1[row], e);
                if (doS) {
                    atomicAdd(&S2[row], s2);
                    atomicAdd(&CNT[row], c);
                }
            }
        }
    }

    // Column-direction reduction for off-diagonal tiles (symmetry).
    if (!diag) {
        #pragma unroll
        for (int n = 0; n < 4; ++n) {
            float ce = colE[n], cs = colS2[n], cc = colC[n];
            const unsigned long long bal = __ballot(cc != 0.f);
            #pragma unroll
            for (int off = 16; off < 64; off <<= 1) ce += __shfl_xor(ce, off);
            if (bal) {
                #pragma unroll
                for (int off = 16; off < 64; off <<= 1) {
                    cs += __shfl_xor(cs, off);
                    cc += __shfl_xor(cc, off);
                }
            }
            if (g16 == 0) {
                const int col = colBase + wc * 64 + n * 16 + l16;
                atomicAdd(&S1[col], ce);
                if (bal) {
                    atomicAdd(&S2[col], cs);
                    atomicAdd(&CNT[col], cc);
                }
            }
        }
    }
}

// ---------------- Kernel 3: finalize ----------------
__global__ __launch_bounds__(1024) void kfinal(const float* __restrict__ S1,
                                               const float* __restrict__ S2,
                                               const float* __restrict__ CNT,
                                               float* __restrict__ out) {
    const int t = threadIdx.x;
    float a = 0.f;
    for (int i = t; i < N_ROWS; i += 1024) {
        const float cnt = CNT[i];
        const float ld = logf(S1[i] + 1e-12f);
        a += (cnt * ld - S2[i]) / (cnt + 1e-12f);
    }
    #pragma unroll
    for (int off = 32; off > 0; off >>= 1) a += __shfl_down(a, off);
    __shared__ float red[16];
    if ((t & 63) == 0) red[t >> 6] = a;
    __syncthreads();
    if (t == 0) {
        float s = 0.f;
        #pragma unroll
        for (int i = 0; i < 16; ++i) s += red[i];
        out[0] = s / (float)N_ROWS;
    }
}

extern "C" void kernel_launch(void* const* d_in, const int* in_sizes, int n_in,
                              void* d_out, int out_size, void* d_ws, size_t ws_size,
                              hipStream_t stream) {
    const float* feat = (const float*)d_in[0];
    const int* labels = (const int*)d_in[1];
    float* out = (float*)d_out;

    char* Q = (char*)d_ws;
    float* SC = (float*)((char*)d_ws + (size_t)N_ROWS * DIM);
    float* S1 = SC + N_ROWS;
    float* S2 = S1 + N_ROWS;
    float* CNT = S2 + N_ROWS;

    constexpr int NT = N_ROWS / 128;              // 64 tiles per dim
    constexpr int NBLK = NT * (NT + 1) / 2;       // 2080 triangular blocks

    knorm<<<N_ROWS, 256, 0, stream>>>(feat, Q, SC, S1, S2, CNT);
    kgemm<<<NBLK, 256, 0, stream>>>(Q, SC, labels, S1, S2, CNT);
    kfinal<<<1, 1024, 0, stream>>>(S1, S2, CNT, out);
}